// Round 11
// baseline (1635.519 us; speedup 1.0000x reference)
//
#include <hip/hip_runtime.h>
#include <hip/hip_bf16.h>

typedef __attribute__((ext_vector_type(8))) short short8;
typedef __attribute__((ext_vector_type(4))) float floatx4;

#define NB   196     // dst-range buckets: bkt = dst >> 8  (50000/256 -> 196)
#define NBLK 256     // edge-chunk blocks for binning

__device__ __forceinline__ float bf_lo(unsigned int u) { return __uint_as_float(u << 16); }
__device__ __forceinline__ float bf_hi(unsigned int u) { return __uint_as_float(u & 0xffff0000u); }

__device__ __forceinline__ unsigned short f2bf_rne(float f) {
    unsigned u = __float_as_uint(f);
    unsigned rb = (u >> 16) & 1u;
    u += 0x7fffu + rb;
    return (unsigned short)(u >> 16);
}
__device__ __forceinline__ unsigned int pack_bf2(float x, float y) {
    return (unsigned int)f2bf_rne(x) | ((unsigned int)f2bf_rne(y) << 16);
}

// ---------------- prep: binA bucket-histogram (blocks [0,NBLK)) + convert/pack (rest) ----------------

__global__ __launch_bounds__(256) void prep_kernel(const int* __restrict__ dst,
                                                   int* __restrict__ blockcnt,   // [NB*NBLK]
                                                   int E,
                                                   const float* __restrict__ x,
                                                   const float* __restrict__ W1,
                                                   const float* __restrict__ W2,
                                                   const float* __restrict__ W3,
                                                   const float* __restrict__ Wp, const float* __restrict__ bp,
                                                   const float* __restrict__ Wc, const float* __restrict__ bc,
                                                   unsigned int* __restrict__ xb,
                                                   unsigned int* __restrict__ W1b,
                                                   unsigned int* __restrict__ W2b,
                                                   unsigned int* __restrict__ W3b,
                                                   unsigned int* __restrict__ Whb,
                                                   float* __restrict__ hbias,
                                                   int nx) {
    if ((int)blockIdx.x < NBLK) {
        __shared__ int hist[NB];
        for (int i = threadIdx.x; i < NB; i += 256) hist[i] = 0;
        __syncthreads();
        const int chunk = (E + NBLK - 1) / NBLK;
        const int lo = blockIdx.x * chunk;
        const int hi = min(lo + chunk, E);
        for (int e = lo + threadIdx.x; e < hi; e += 256)
            atomicAdd(&hist[dst[e] >> 8], 1);          // LDS atomic, block-local
        __syncthreads();
        for (int i = threadIdx.x; i < NB; i += 256)
            blockcnt[i * NBLK + blockIdx.x] = hist[i]; // bucket-major layout for scan
        return;
    }
    int i = (blockIdx.x - NBLK) * 256 + threadIdx.x;
    const int T0 = nx;            // x pairs
    const int T1 = T0 + 4096;     // W1 128x64
    const int T2 = T1 + 8192;     // W2 128x128
    const int T3 = T2 + 4096;     // W3 64x128
    const int T4 = T3 + 2560;     // Whb 80x64
    const int T5 = T4 + 80;       // hbias
    if (i < T0) {
        float2 f = ((const float2*)x)[i];
        xb[i] = pack_bf2(f.x, f.y);
    } else if (i < T1) {
        float2 f = ((const float2*)W1)[i - T0];
        W1b[i - T0] = pack_bf2(f.x, f.y);
    } else if (i < T2) {
        float2 f = ((const float2*)W2)[i - T1];
        W2b[i - T1] = pack_bf2(f.x, f.y);
    } else if (i < T3) {
        float2 f = ((const float2*)W3)[i - T2];
        W3b[i - T2] = pack_bf2(f.x, f.y);
    } else if (i < T4) {
        int j = i - T3;
        int r = j >> 5, c = (j & 31) * 2;
        float v0 = 0.f, v1 = 0.f;
        if (r < 64)      { v0 = Wp[r * 64 + c]; v1 = Wp[r * 64 + c + 1]; }
        else if (r < 74) { v0 = Wc[(r - 64) * 64 + c]; v1 = Wc[(r - 64) * 64 + c + 1]; }
        Whb[j] = pack_bf2(v0, v1);
    } else if (i < T5) {
        int j = i - T4;
        float v = 0.f;
        if (j < 64)      v = bp[j];
        else if (j < 74) v = bc[j - 64];
        hbias[j] = v;
    }
}

// ---------------- scan over blockcnt (items = NB*NBLK) -> exact exclusive base ----------------

__global__ __launch_bounds__(256) void partial_sum_kernel(const int* __restrict__ v,
                                                          int* __restrict__ partial, int n) {
    __shared__ int s[256];
    int t = threadIdx.x;
    int i = blockIdx.x * 256 + t;
    s[t] = (i < n) ? v[i] : 0;
    __syncthreads();
    for (int off = 128; off > 0; off >>= 1) {
        if (t < off) s[t] += s[t + off];
        __syncthreads();
    }
    if (t == 0) partial[blockIdx.x] = s[0];
}

__global__ __launch_bounds__(256) void local_scan_kernel(const int* __restrict__ v,
                                                         const int* __restrict__ partial,
                                                         int* __restrict__ base,
                                                         int nblocks, int n) {
    __shared__ int sp[256];
    __shared__ int s[256];
    int t = threadIdx.x;
    sp[t] = (t < nblocks) ? partial[t] : 0;
    __syncthreads();
    for (int off = 1; off < 256; off <<= 1) {
        int u = (t >= off) ? sp[t - off] : 0;
        __syncthreads();
        sp[t] += u;
        __syncthreads();
    }
    const int blockbase = (blockIdx.x == 0) ? 0 : sp[blockIdx.x - 1];
    if (blockIdx.x == 0 && t == 0) base[n] = sp[nblocks - 1];   // total = E

    int i = blockIdx.x * 256 + t;
    int w = (i < n) ? v[i] : 0;
    s[t] = w;
    __syncthreads();
    for (int off = 1; off < 256; off <<= 1) {
        int u = (t >= off) ? s[t - off] : 0;
        __syncthreads();
        s[t] += u;
        __syncthreads();
    }
    if (i < n) base[i] = blockbase + s[t] - w;   // exclusive prefix
}

// ---------------- binC: rank within (block,bucket) in LDS, write packed pairs ----------------

__global__ __launch_bounds__(256) void binC_kernel(const int* __restrict__ src,
                                                   const int* __restrict__ dst,
                                                   const int* __restrict__ base,
                                                   unsigned int* __restrict__ pairs, int E) {
    __shared__ int bbase[NB];
    __shared__ int cur[NB];
    for (int i = threadIdx.x; i < NB; i += 256) {
        bbase[i] = base[i * NBLK + blockIdx.x];
        cur[i] = 0;
    }
    __syncthreads();
    const int chunk = (E + NBLK - 1) / NBLK;
    const int lo = blockIdx.x * chunk;
    const int hi = min(lo + chunk, E);
    for (int e = lo + threadIdx.x; e < hi; e += 256) {
        int d = dst[e];
        int b = d >> 8;
        int r = atomicAdd(&cur[b], 1);                 // LDS atomic, block-local
        pairs[bbase[b] + r] = ((unsigned)d << 16) | (unsigned)src[e];
    }
}

// ---------------- bucketD: per-node count+scan in LDS -> offsets + csr scatter ----------------
// csr entry = ((dst & 31) << 16) | src : local node id within its 32-node group + source.

__global__ __launch_bounds__(256) void bucketD_kernel(const unsigned int* __restrict__ pairs,
                                                      const int* __restrict__ base,
                                                      int* __restrict__ offsets,
                                                      unsigned int* __restrict__ csr,
                                                      int E, int n) {
    __shared__ int cnt[256];
    __shared__ int loc[256];
    const int b = blockIdx.x;
    const int start = base[b * NBLK];
    const int end   = base[(b + 1) * NBLK];   // b=NB-1 reads base[NB*NBLK] = E
    const int t = threadIdx.x;

    cnt[t] = 0;
    __syncthreads();
    for (int i = start + t; i < end; i += 256)
        atomicAdd(&cnt[(pairs[i] >> 16) & 255], 1);    // local node index = dst & 255
    __syncthreads();

    loc[t] = cnt[t];
    __syncthreads();
    for (int off = 1; off < 256; off <<= 1) {
        int u = (t >= off) ? loc[t - off] : 0;
        __syncthreads();
        loc[t] += u;
        __syncthreads();
    }
    const int excl = (t == 0) ? 0 : loc[t - 1];

    const int d = (b << 8) + t;
    if (d < n) offsets[d] = start + excl;
    if (b == 0 && t == 0) offsets[n] = E;

    __syncthreads();
    cnt[t] = excl;            // cursor = local exclusive prefix
    __syncthreads();
    for (int i = start + t; i < end; i += 256) {
        unsigned pr = pairs[i];
        int j = (pr >> 16) & 255;
        int p = atomicAdd(&cnt[j], 1);                 // LDS atomic, block-local
        csr[start + p] = (((pr >> 16) & 31u) << 16) | (pr & 0xffffu);
    }
}

// ---------------- Fused agg + MFMA GEMM per layer ----------------
// Block = 512 threads, 32 nodes (contiguous csr range). Phase A (edge-parallel):
// each half-wave (F=128; quarter-wave for F=64) processes one edge: broadcast csr
// entry, gather the full row (8B/lane), atomicAdd 4 floats into LDS fp32 accum.
// Slot layout slot=k*(F/4)+c makes each add conflict-free (<=2-way). Perfect
// intra-block load balance (vs the old wave-max-degree serial loop). Accum order
// is nondeterministic (LDS atomics) - fp32 reorder noise ~1e-5, under tolerance.
// Normalize: /deg + self row + pack bf16 -> Ht. Phase B: MFMA (unchanged).
// MODE 0: bf16 out + relu.  MODE 3: relu, fp32 emb out, heads MFMA via LDS Ytile.

template <int F_IN, int F_OUT, int MODE>
__global__ __launch_bounds__(512) void fused_agg_gemm_kernel(
        const unsigned long long* __restrict__ xt,      // gather table, F_IN/4 u64 per row
        const int* __restrict__ offsets,
        const unsigned int* __restrict__ csr,           // ((dst&31)<<16)|src
        const unsigned short* __restrict__ Wb,          // F_OUT x F_IN bf16
        const float* __restrict__ bias,
        unsigned short* __restrict__ Yb,                // MODE 0 out
        float* __restrict__ Yf,                         // MODE 3: emb out (fp32)
        float* __restrict__ nev, float* __restrict__ cls,
        const unsigned short* __restrict__ Whb, const float* __restrict__ hbias,
        int n) {
    constexpr int KC   = F_IN / 32;     // short8 chunks per row
    constexpr int XSTR = F_IN / 4;      // u64 per gather-table row
    constexpr int NC   = F_IN / 4;      // u64 cols per row
    constexpr int HSTR = F_IN + 8;      // LDS row stride (shorts)
    constexpr int ASTR = F_IN + 8;      // accum row stride (floats), breaks pow2
    __shared__ float acc[32][ASTR];
    __shared__ __align__(16) unsigned short Ht[32 * HSTR];
    __shared__ __align__(16) unsigned short Yt[(MODE == 3) ? 32 * 72 : 16];
    __shared__ int ofs[33];

    const int tid  = threadIdx.x;
    const int lane = tid & 63;
    const int wv   = tid >> 6;
    const int m0   = blockIdx.x * 32;

    if (tid < 33) ofs[tid] = offsets[min(m0 + tid, n)];
    for (int i = tid; i < 32 * ASTR; i += 512) ((float*)acc)[i] = 0.f;
    __syncthreads();

    const int s0 = ofs[0], s1 = ofs[32];

    // ---------- Phase A: edge-parallel gather + LDS fp32 accumulate ----------
    if (F_IN == 128) {
        const int hw = tid >> 5;       // half-wave 0..15, one edge each
        const int c  = tid & 31;       // u64 col
        int e = s0 + hw;
        for (; e + 48 < s1; e += 64) {
            unsigned p0 = csr[e], p1 = csr[e + 16], p2 = csr[e + 32], p3 = csr[e + 48];
            unsigned long long v0 = xt[(size_t)(p0 & 0xffffu) * XSTR + c];
            unsigned long long v1 = xt[(size_t)(p1 & 0xffffu) * XSTR + c];
            unsigned long long v2 = xt[(size_t)(p2 & 0xffffu) * XSTR + c];
            unsigned long long v3 = xt[(size_t)(p3 & 0xffffu) * XSTR + c];
            int l0 = (p0 >> 16) & 31, l1 = (p1 >> 16) & 31;
            int l2 = (p2 >> 16) & 31, l3 = (p3 >> 16) & 31;
            atomicAdd(&acc[l0][0 * 32 + c], bf_lo((unsigned)v0));
            atomicAdd(&acc[l0][1 * 32 + c], bf_hi((unsigned)v0));
            atomicAdd(&acc[l0][2 * 32 + c], bf_lo((unsigned)(v0 >> 32)));
            atomicAdd(&acc[l0][3 * 32 + c], bf_hi((unsigned)(v0 >> 32)));
            atomicAdd(&acc[l1][0 * 32 + c], bf_lo((unsigned)v1));
            atomicAdd(&acc[l1][1 * 32 + c], bf_hi((unsigned)v1));
            atomicAdd(&acc[l1][2 * 32 + c], bf_lo((unsigned)(v1 >> 32)));
            atomicAdd(&acc[l1][3 * 32 + c], bf_hi((unsigned)(v1 >> 32)));
            atomicAdd(&acc[l2][0 * 32 + c], bf_lo((unsigned)v2));
            atomicAdd(&acc[l2][1 * 32 + c], bf_hi((unsigned)v2));
            atomicAdd(&acc[l2][2 * 32 + c], bf_lo((unsigned)(v2 >> 32)));
            atomicAdd(&acc[l2][3 * 32 + c], bf_hi((unsigned)(v2 >> 32)));
            atomicAdd(&acc[l3][0 * 32 + c], bf_lo((unsigned)v3));
            atomicAdd(&acc[l3][1 * 32 + c], bf_hi((unsigned)v3));
            atomicAdd(&acc[l3][2 * 32 + c], bf_lo((unsigned)(v3 >> 32)));
            atomicAdd(&acc[l3][3 * 32 + c], bf_hi((unsigned)(v3 >> 32)));
        }
        for (; e < s1; e += 16) {
            unsigned p = csr[e];
            unsigned long long v = xt[(size_t)(p & 0xffffu) * XSTR + c];
            int l = (p >> 16) & 31;
            atomicAdd(&acc[l][0 * 32 + c], bf_lo((unsigned)v));
            atomicAdd(&acc[l][1 * 32 + c], bf_hi((unsigned)v));
            atomicAdd(&acc[l][2 * 32 + c], bf_lo((unsigned)(v >> 32)));
            atomicAdd(&acc[l][3 * 32 + c], bf_hi((unsigned)(v >> 32)));
        }
    } else {
        const int qw = tid >> 4;       // quarter-wave 0..31, one edge each
        const int c  = tid & 15;       // u64 col
        int e = s0 + qw;
        for (; e + 96 < s1; e += 128) {
            unsigned p0 = csr[e], p1 = csr[e + 32], p2 = csr[e + 64], p3 = csr[e + 96];
            unsigned long long v0 = xt[(size_t)(p0 & 0xffffu) * XSTR + c];
            unsigned long long v1 = xt[(size_t)(p1 & 0xffffu) * XSTR + c];
            unsigned long long v2 = xt[(size_t)(p2 & 0xffffu) * XSTR + c];
            unsigned long long v3 = xt[(size_t)(p3 & 0xffffu) * XSTR + c];
            int l0 = (p0 >> 16) & 31, l1 = (p1 >> 16) & 31;
            int l2 = (p2 >> 16) & 31, l3 = (p3 >> 16) & 31;
            atomicAdd(&acc[l0][0 * 16 + c], bf_lo((unsigned)v0));
            atomicAdd(&acc[l0][1 * 16 + c], bf_hi((unsigned)v0));
            atomicAdd(&acc[l0][2 * 16 + c], bf_lo((unsigned)(v0 >> 32)));
            atomicAdd(&acc[l0][3 * 16 + c], bf_hi((unsigned)(v0 >> 32)));
            atomicAdd(&acc[l1][0 * 16 + c], bf_lo((unsigned)v1));
            atomicAdd(&acc[l1][1 * 16 + c], bf_hi((unsigned)v1));
            atomicAdd(&acc[l1][2 * 16 + c], bf_lo((unsigned)(v1 >> 32)));
            atomicAdd(&acc[l1][3 * 16 + c], bf_hi((unsigned)(v1 >> 32)));
            atomicAdd(&acc[l2][0 * 16 + c], bf_lo((unsigned)v2));
            atomicAdd(&acc[l2][1 * 16 + c], bf_hi((unsigned)v2));
            atomicAdd(&acc[l2][2 * 16 + c], bf_lo((unsigned)(v2 >> 32)));
            atomicAdd(&acc[l2][3 * 16 + c], bf_hi((unsigned)(v2 >> 32)));
            atomicAdd(&acc[l3][0 * 16 + c], bf_lo((unsigned)v3));
            atomicAdd(&acc[l3][1 * 16 + c], bf_hi((unsigned)v3));
            atomicAdd(&acc[l3][2 * 16 + c], bf_lo((unsigned)(v3 >> 32)));
            atomicAdd(&acc[l3][3 * 16 + c], bf_hi((unsigned)(v3 >> 32)));
        }
        for (; e < s1; e += 32) {
            unsigned p = csr[e];
            unsigned long long v = xt[(size_t)(p & 0xffffu) * XSTR + c];
            int l = (p >> 16) & 31;
            atomicAdd(&acc[l][0 * 16 + c], bf_lo((unsigned)v));
            atomicAdd(&acc[l][1 * 16 + c], bf_hi((unsigned)v));
            atomicAdd(&acc[l][2 * 16 + c], bf_lo((unsigned)(v >> 32)));
            atomicAdd(&acc[l][3 * 16 + c], bf_hi((unsigned)(v >> 32)));
        }
    }
    __syncthreads();

    // ---------- Normalize: /deg + self + pack bf16 into Ht ----------
    for (int t = tid; t < 32 * NC; t += 512) {
        const int lc = t / NC;
        const int cc = t % NC;
        const int node = m0 + lc;
        if (node < n) {
            const int deg = ofs[lc + 1] - ofs[lc];
            const float inv = 1.0f / fmaxf((float)deg, 1.0f);
            unsigned long long sv = xt[(size_t)node * XSTR + cc];
            float f0 = acc[lc][0 * NC + cc] * inv + bf_lo((unsigned)sv);
            float f1 = acc[lc][1 * NC + cc] * inv + bf_hi((unsigned)sv);
            float f2 = acc[lc][2 * NC + cc] * inv + bf_lo((unsigned)(sv >> 32));
            float f3 = acc[lc][3 * NC + cc] * inv + bf_hi((unsigned)(sv >> 32));
            unsigned o0 = pack_bf2(f0, f1), o1 = pack_bf2(f2, f3);
            *(unsigned long long*)&Ht[lc * HSTR + cc * 4] =
                ((unsigned long long)o1 << 32) | o0;
        } else {
            *(unsigned long long*)&Ht[lc * HSTR + cc * 4] = 0ull;
        }
    }
    __syncthreads();

    // ---------- Phase B: MFMA on the 32-row tile ----------
    const int quad = lane >> 4;
    const int r16  = lane & 15;

    if (MODE == 0) {
        // 32 x F_OUT(=128): 2 row-groups x 8 col-groups = 16 tiles, 2 per wave
        const int rowg = wv & 1;
        const int cg0  = (wv >> 1) * 2;
        short8 a[KC];
#pragma unroll
        for (int c = 0; c < KC; ++c)
            a[c] = *(const short8*)&Ht[(16 * rowg + r16) * HSTR + 32 * c + quad * 8];

        floatx4 acc2[2];
#pragma unroll
        for (int j = 0; j < 2; ++j)
#pragma unroll
            for (int r = 0; r < 4; ++r) acc2[j][r] = 0.f;

#pragma unroll
        for (int j = 0; j < 2; ++j)
#pragma unroll
            for (int c = 0; c < KC; ++c) {
                short8 b = *(const short8*)&Wb[(size_t)(16 * (cg0 + j) + r16) * F_IN + 32 * c + quad * 8];
                acc2[j] = __builtin_amdgcn_mfma_f32_16x16x32_bf16(a[c], b, acc2[j], 0, 0, 0);
            }

#pragma unroll
        for (int r = 0; r < 4; ++r) {
            const int mm = m0 + 16 * rowg + quad * 4 + r;
            if (mm >= n) continue;
#pragma unroll
            for (int j = 0; j < 2; ++j) {
                const int o = 16 * (cg0 + j) + r16;
                Yb[(size_t)mm * F_OUT + o] = f2bf_rne(fmaxf(acc2[j][r] + bias[o], 0.f));
            }
        }
    } else {
        // layer3: 32 x 64 = 2 x 4 tiles, 1 per wave; then heads from LDS Ytile
        const int rowg = wv & 1;
        const int cg   = wv >> 1;      // 0..3
        short8 a[KC];
#pragma unroll
        for (int c = 0; c < KC; ++c)
            a[c] = *(const short8*)&Ht[(16 * rowg + r16) * HSTR + 32 * c + quad * 8];

        floatx4 acc1;
#pragma unroll
        for (int r = 0; r < 4; ++r) acc1[r] = 0.f;

#pragma unroll
        for (int c = 0; c < KC; ++c) {
            short8 b = *(const short8*)&Wb[(size_t)(16 * cg + r16) * F_IN + 32 * c + quad * 8];
            acc1 = __builtin_amdgcn_mfma_f32_16x16x32_bf16(a[c], b, acc1, 0, 0, 0);
        }

#pragma unroll
        for (int r = 0; r < 4; ++r) {
            const int lr = 16 * rowg + quad * 4 + r;
            const int mm = m0 + lr;
            const int o  = 16 * cg + r16;
            if (mm < n) {
                float v = fmaxf(acc1[r] + bias[o], 0.f);
                Yf[(size_t)mm * 64 + o] = v;
                Yt[lr * 72 + o] = f2bf_rne(v);
            } else {
                Yt[lr * 72 + o] = 0;
            }
        }
        __syncthreads();

        // heads: 32 x 80 = 2 x 5 tiles = 10, waves 0..7 take t=wv, waves 0..1 also t=8+wv
        for (int t = wv; t < 10; t += 8) {
            const int rg  = t & 1;
            const int cg2 = t >> 1;    // 0..4
            short8 a2[2];
#pragma unroll
            for (int c = 0; c < 2; ++c)
                a2[c] = *(const short8*)&Yt[(16 * rg + r16) * 72 + 32 * c + quad * 8];

            floatx4 acc3;
#pragma unroll
            for (int r = 0; r < 4; ++r) acc3[r] = 0.f;

#pragma unroll
            for (int c = 0; c < 2; ++c) {
                short8 b = *(const short8*)&Whb[(size_t)(16 * cg2 + r16) * 64 + 32 * c + quad * 8];
                acc3 = __builtin_amdgcn_mfma_f32_16x16x32_bf16(a2[c], b, acc3, 0, 0, 0);
            }

#pragma unroll
            for (int r = 0; r < 4; ++r) {
                const int mm = m0 + 16 * rg + quad * 4 + r;
                if (mm >= n) continue;
                const int o = 16 * cg2 + r16;
                float v = acc3[r] + hbias[o];
                if (o < 64)      nev[(size_t)mm * 64 + o] = v;
                else if (o < 74) cls[(size_t)mm * 10 + (o - 64)] = v;
            }
        }
    }
}

// ---------------- launch ----------------

extern "C" void kernel_launch(void* const* d_in, const int* in_sizes, int n_in,
                              void* d_out, int out_size, void* d_ws, size_t ws_size,
                              hipStream_t stream) {
    const float* x  = (const float*)d_in[0];
    const int*   ei = (const int*)d_in[1];
    const float* W1 = (const float*)d_in[2];
    const float* b1 = (const float*)d_in[3];
    const float* W2 = (const float*)d_in[4];
    const float* b2 = (const float*)d_in[5];
    const float* W3 = (const float*)d_in[6];
    const float* b3 = (const float*)d_in[7];
    const float* Wp = (const float*)d_in[8];
    const float* bp = (const float*)d_in[9];
    const float* Wc = (const float*)d_in[10];
    const float* bc = (const float*)d_in[11];

    const int n = in_sizes[0] / 64;   // 50000
    const int E = in_sizes[1] / 2;    // 800000
    const int* src = ei;
    const int* dst = ei + E;

    const int items = NB * NBLK;                 // 50176
    const int nScan = (items + 255) / 256;       // 196

    // workspace layout (no memset, no global atomics)
    int* blockcnt = (int*)d_ws;                    // items
    int* base     = blockcnt + items;              // items + 1
    int* partial  = base + items + 1;              // 256
    int* offsets  = partial + 256;                 // n + 1
    unsigned int* pairs = (unsigned int*)(offsets + n + 1);   // E u32 (dst<<16|src)
    unsigned int* csr   = pairs + E;                          // E u32 ((dst&31)<<16|src)
    uintptr_t p = (uintptr_t)(csr + E);
    p = (p + 255) & ~(uintptr_t)255;
    unsigned int* Hb  = (unsigned int*)p;          // n*64 (n x 128 bf16)
    unsigned int* Yb  = Hb + (size_t)n * 64;       // n*64 (n x 128 bf16)
    unsigned int* xb  = Yb + (size_t)n * 64;       // n*32 (n x 64 bf16)
    unsigned int* W1b = xb + (size_t)n * 32;       // 4096 uints
    unsigned int* W2b = W1b + 4096;                // 8192
    unsigned int* W3b = W2b + 8192;                // 4096
    unsigned int* Whb = W3b + 4096;                // 2560
    float* hbias = (float*)(Whb + 2560);           // 80

    float* out_emb = (float*)d_out;
    float* out_nev = out_emb + (size_t)n * 64;
    float* out_cls = out_nev + (size_t)n * 64;

    const int convTotal = n * 32 + 4096 + 8192 + 4096 + 2560 + 80;
    const int convBlocks = (convTotal + 255) / 256;
    prep_kernel<<<NBLK + convBlocks, 256, 0, stream>>>(
        dst, blockcnt, E,
        x, W1, W2, W3, Wp, bp, Wc, bc, xb, W1b, W2b, W3b, Whb, hbias, n * 32);

    partial_sum_kernel<<<nScan, 256, 0, stream>>>(blockcnt, partial, items);
    local_scan_kernel<<<nScan, 256, 0, stream>>>(blockcnt, partial, base, nScan, items);

    binC_kernel<<<NBLK, 256, 0, stream>>>(src, dst, base, pairs, E);
    bucketD_kernel<<<NB, 256, 0, stream>>>(pairs, base, offsets, csr, E, n);

    const int gF = (n + 31) / 32;    // 1563 blocks, 512 threads

    // layer 1: agg(xb, F=64) + GEMM 64->128 -> Hb (bf16)
    fused_agg_gemm_kernel<64, 128, 0><<<gF, 512, 0, stream>>>(
        (const unsigned long long*)xb, offsets, csr,
        (const unsigned short*)W1b, b1, (unsigned short*)Hb,
        nullptr, nullptr, nullptr, nullptr, nullptr, n);

    // layer 2: agg(Hb, F=128) + GEMM 128->128 -> Yb (bf16)
    fused_agg_gemm_kernel<128, 128, 0><<<gF, 512, 0, stream>>>(
        (const unsigned long long*)Hb, offsets, csr,
        (const unsigned short*)W2b, b2, (unsigned short*)Yb,
        nullptr, nullptr, nullptr, nullptr, nullptr, n);

    // layer 3: agg(Yb, F=128) + GEMM 128->64 + heads -> out_emb / nev / cls
    fused_agg_gemm_kernel<128, 64, 3><<<gF, 512, 0, stream>>>(
        (const unsigned long long*)Yb, offsets, csr,
        (const unsigned short*)W3b, b3, nullptr,
        out_emb, out_nev, out_cls, (const unsigned short*)Whb, hbias, n);
}

// Round 12
// 246.617 us; speedup vs baseline: 6.6318x; 6.6318x over previous
//
#include <hip/hip_runtime.h>
#include <hip/hip_bf16.h>

typedef __attribute__((ext_vector_type(8))) short short8;
typedef __attribute__((ext_vector_type(4))) float floatx4;

#define NB   196     // dst-range buckets: bkt = dst >> 8  (50000/256 -> 196)
#define NBLK 256     // edge-chunk blocks for binning

__device__ __forceinline__ float bf_lo(unsigned int u) { return __uint_as_float(u << 16); }
__device__ __forceinline__ float bf_hi(unsigned int u) { return __uint_as_float(u & 0xffff0000u); }

__device__ __forceinline__ unsigned short f2bf_rne(float f) {
    unsigned u = __float_as_uint(f);
    unsigned rb = (u >> 16) & 1u;
    u += 0x7fffu + rb;
    return (unsigned short)(u >> 16);
}
__device__ __forceinline__ unsigned int pack_bf2(float x, float y) {
    return (unsigned int)f2bf_rne(x) | ((unsigned int)f2bf_rne(y) << 16);
}

__device__ __forceinline__ void acc4(unsigned long long v, float& f0, float& f1, float& f2, float& f3) {
    unsigned ua = (unsigned)v, ub = (unsigned)(v >> 32);
    f0 += bf_lo(ua); f1 += bf_hi(ua); f2 += bf_lo(ub); f3 += bf_hi(ub);
}

// ---------------- prep: binA bucket-histogram (blocks [0,NBLK)) + convert/pack (rest) ----------------

__global__ __launch_bounds__(256) void prep_kernel(const int* __restrict__ dst,
                                                   int* __restrict__ blockcnt,   // [NB*NBLK]
                                                   int E,
                                                   const float* __restrict__ x,
                                                   const float* __restrict__ W1,
                                                   const float* __restrict__ W2,
                                                   const float* __restrict__ W3,
                                                   const float* __restrict__ Wp, const float* __restrict__ bp,
                                                   const float* __restrict__ Wc, const float* __restrict__ bc,
                                                   unsigned int* __restrict__ xb,
                                                   unsigned int* __restrict__ W1b,
                                                   unsigned int* __restrict__ W2b,
                                                   unsigned int* __restrict__ W3b,
                                                   unsigned int* __restrict__ Whb,
                                                   float* __restrict__ hbias,
                                                   int nx) {
    if ((int)blockIdx.x < NBLK) {
        __shared__ int hist[NB];
        for (int i = threadIdx.x; i < NB; i += 256) hist[i] = 0;
        __syncthreads();
        const int chunk = (E + NBLK - 1) / NBLK;
        const int lo = blockIdx.x * chunk;
        const int hi = min(lo + chunk, E);
        for (int e = lo + threadIdx.x; e < hi; e += 256)
            atomicAdd(&hist[dst[e] >> 8], 1);          // LDS atomic, block-local
        __syncthreads();
        for (int i = threadIdx.x; i < NB; i += 256)
            blockcnt[i * NBLK + blockIdx.x] = hist[i]; // bucket-major layout for scan
        return;
    }
    int i = (blockIdx.x - NBLK) * 256 + threadIdx.x;
    const int T0 = nx;            // x pairs
    const int T1 = T0 + 4096;     // W1 128x64
    const int T2 = T1 + 8192;     // W2 128x128
    const int T3 = T2 + 4096;     // W3 64x128
    const int T4 = T3 + 2560;     // Whb 80x64
    const int T5 = T4 + 80;       // hbias
    if (i < T0) {
        float2 f = ((const float2*)x)[i];
        xb[i] = pack_bf2(f.x, f.y);
    } else if (i < T1) {
        float2 f = ((const float2*)W1)[i - T0];
        W1b[i - T0] = pack_bf2(f.x, f.y);
    } else if (i < T2) {
        float2 f = ((const float2*)W2)[i - T1];
        W2b[i - T1] = pack_bf2(f.x, f.y);
    } else if (i < T3) {
        float2 f = ((const float2*)W3)[i - T2];
        W3b[i - T2] = pack_bf2(f.x, f.y);
    } else if (i < T4) {
        int j = i - T3;
        int r = j >> 5, c = (j & 31) * 2;
        float v0 = 0.f, v1 = 0.f;
        if (r < 64)      { v0 = Wp[r * 64 + c]; v1 = Wp[r * 64 + c + 1]; }
        else if (r < 74) { v0 = Wc[(r - 64) * 64 + c]; v1 = Wc[(r - 64) * 64 + c + 1]; }
        Whb[j] = pack_bf2(v0, v1);
    } else if (i < T5) {
        int j = i - T4;
        float v = 0.f;
        if (j < 64)      v = bp[j];
        else if (j < 74) v = bc[j - 64];
        hbias[j] = v;
    }
}

// ---------------- scan over blockcnt (items = NB*NBLK) -> exact exclusive base ----------------

__global__ __launch_bounds__(256) void partial_sum_kernel(const int* __restrict__ v,
                                                          int* __restrict__ partial, int n) {
    __shared__ int s[256];
    int t = threadIdx.x;
    int i = blockIdx.x * 256 + t;
    s[t] = (i < n) ? v[i] : 0;
    __syncthreads();
    for (int off = 128; off > 0; off >>= 1) {
        if (t < off) s[t] += s[t + off];
        __syncthreads();
    }
    if (t == 0) partial[blockIdx.x] = s[0];
}

__global__ __launch_bounds__(256) void local_scan_kernel(const int* __restrict__ v,
                                                         const int* __restrict__ partial,
                                                         int* __restrict__ base,
                                                         int nblocks, int n) {
    __shared__ int sp[256];
    __shared__ int s[256];
    int t = threadIdx.x;
    sp[t] = (t < nblocks) ? partial[t] : 0;
    __syncthreads();
    for (int off = 1; off < 256; off <<= 1) {
        int u = (t >= off) ? sp[t - off] : 0;
        __syncthreads();
        sp[t] += u;
        __syncthreads();
    }
    const int blockbase = (blockIdx.x == 0) ? 0 : sp[blockIdx.x - 1];
    if (blockIdx.x == 0 && t == 0) base[n] = sp[nblocks - 1];   // total = E

    int i = blockIdx.x * 256 + t;
    int w = (i < n) ? v[i] : 0;
    s[t] = w;
    __syncthreads();
    for (int off = 1; off < 256; off <<= 1) {
        int u = (t >= off) ? s[t - off] : 0;
        __syncthreads();
        s[t] += u;
        __syncthreads();
    }
    if (i < n) base[i] = blockbase + s[t] - w;   // exclusive prefix
}

// ---------------- binC: rank within (block,bucket) in LDS, write packed pairs ----------------

__global__ __launch_bounds__(256) void binC_kernel(const int* __restrict__ src,
                                                   const int* __restrict__ dst,
                                                   const int* __restrict__ base,
                                                   unsigned int* __restrict__ pairs, int E) {
    __shared__ int bbase[NB];
    __shared__ int cur[NB];
    for (int i = threadIdx.x; i < NB; i += 256) {
        bbase[i] = base[i * NBLK + blockIdx.x];
        cur[i] = 0;
    }
    __syncthreads();
    const int chunk = (E + NBLK - 1) / NBLK;
    const int lo = blockIdx.x * chunk;
    const int hi = min(lo + chunk, E);
    for (int e = lo + threadIdx.x; e < hi; e += 256) {
        int d = dst[e];
        int b = d >> 8;
        int r = atomicAdd(&cur[b], 1);                 // LDS atomic, block-local
        pairs[bbase[b] + r] = ((unsigned)d << 16) | (unsigned)src[e];
    }
}

// ---------------- bucketD: per-node count+scan in LDS -> offsets + csr scatter ----------------

__global__ __launch_bounds__(256) void bucketD_kernel(const unsigned int* __restrict__ pairs,
                                                      const int* __restrict__ base,
                                                      int* __restrict__ offsets,
                                                      unsigned short* __restrict__ csr_src,
                                                      int E, int n) {
    __shared__ int cnt[256];
    __shared__ int loc[256];
    const int b = blockIdx.x;
    const int start = base[b * NBLK];
    const int end   = base[(b + 1) * NBLK];   // b=NB-1 reads base[NB*NBLK] = E
    const int t = threadIdx.x;

    cnt[t] = 0;
    __syncthreads();
    for (int i = start + t; i < end; i += 256)
        atomicAdd(&cnt[(pairs[i] >> 16) & 255], 1);    // local node index = dst & 255
    __syncthreads();

    loc[t] = cnt[t];
    __syncthreads();
    for (int off = 1; off < 256; off <<= 1) {
        int u = (t >= off) ? loc[t - off] : 0;
        __syncthreads();
        loc[t] += u;
        __syncthreads();
    }
    const int excl = (t == 0) ? 0 : loc[t - 1];

    const int d = (b << 8) + t;
    if (d < n) offsets[d] = start + excl;
    if (b == 0 && t == 0) offsets[n] = E;

    __syncthreads();
    cnt[t] = excl;            // cursor = local exclusive prefix
    __syncthreads();
    for (int i = start + t; i < end; i += 256) {
        unsigned pr = pairs[i];
        int j = (pr >> 16) & 255;
        int p = atomicAdd(&cnt[j], 1);                 // LDS atomic, block-local
        csr_src[start + p] = (unsigned short)(pr & 0xffffu);
    }
}

// ---------------- Fused agg + MFMA GEMM per layer ----------------
// Block = 512 threads (8 waves), 32 nodes. Phase A: one node per LANE GROUP —
// F=64: 4 nodes/wave (16-lane groups), 16-deep batches (proven round-9 form).
// F=128 (this round's single change): the two per-wave node passes are INTERLEAVED
// — both nodes' 16-gather batches issue back-to-back (32 loads / 8KB in flight,
// 2x MLP), separate register accumulators, per-node accumulation order unchanged
// (bit-identical numerics). MLP probe: if fetch path is a hard ceiling, no change.
// Phase B: 8 waves MFMA the 32xF_OUT tile from LDS.
// MODE 0: bf16 out + relu.  MODE 3: relu, fp32 emb out, heads MFMA via LDS Ytile.

template <int F_IN, int F_OUT, int MODE>
__global__ __launch_bounds__(512) void fused_agg_gemm_kernel(
        const unsigned long long* __restrict__ xt,      // gather table, F_IN/4 u64 per row
        const int* __restrict__ offsets,
        const unsigned short* __restrict__ csr_src,
        const unsigned short* __restrict__ Wb,          // F_OUT x F_IN bf16
        const float* __restrict__ bias,
        unsigned short* __restrict__ Yb,                // MODE 0 out
        float* __restrict__ Yf,                         // MODE 3: emb out (fp32)
        float* __restrict__ nev, float* __restrict__ cls,
        const unsigned short* __restrict__ Whb, const float* __restrict__ hbias,
        int n) {
    constexpr int KC   = F_IN / 32;     // short8 chunks per row
    constexpr int XSTR = F_IN / 4;      // u64 per gather-table row
    constexpr int HSTR = F_IN + 8;      // LDS row stride (shorts), breaks pow2 banks
    __shared__ __align__(16) unsigned short Ht[32 * HSTR];
    __shared__ __align__(16) unsigned short Yt[(MODE == 3) ? 32 * 72 : 16];

    const int lane = threadIdx.x & 63;
    const int wv   = threadIdx.x >> 6;      // 0..7
    const int m0   = blockIdx.x * 32;

    // ---------- Phase A ----------
    if (F_IN == 64) {
        const int g   = lane >> 4;          // node group 0..3
        const int c   = lane & 15;          // u64 col within row
        const int row = wv * 4 + g;
        const int node = m0 + row;
        int ns = 0, ne = 0;
        if (node < n) { ns = offsets[node]; ne = offsets[node + 1]; }
        const int cnt = ne - ns;
        unsigned long long sv = (node < n) ? xt[(size_t)node * XSTR + c] : 0ull;

        int mc = cnt;
        mc = max(mc, __shfl(mc, lane ^ 16, 64));
        mc = max(mc, __shfl(mc, lane ^ 32, 64));    // wave-max edge count

        float s0 = 0.f, s1 = 0.f, s2 = 0.f, s3 = 0.f;
        int ii0 = ns + c;
        if (cnt > 0) { if (ii0 >= ne) ii0 = ne - 1; } else ii0 = 0;
        int idx = (mc > 0) ? (int)csr_src[ii0] : 0;

        for (int base = 0; base < mc; base += 16) {
            int idxN = 0;                            // prefetch next stripe's csr
            if (base + 16 < mc) {
                int ii = ns + base + 16 + c;
                if (cnt > 0) { if (ii >= ne) ii = ne - 1; } else ii = 0;
                idxN = csr_src[ii];
            }
            unsigned long long v[16];
#pragma unroll
            for (int q = 0; q < 16; ++q) {
                int nb = __shfl(idx, g * 16 + q, 64);   // all lanes execute
                if (base + q < cnt) v[q] = xt[(size_t)nb * XSTR + c];
            }
#pragma unroll
            for (int q = 0; q < 16; ++q)
                if (base + q < cnt) acc4(v[q], s0, s1, s2, s3);
            idx = idxN;
        }
        float inv = 1.0f / fmaxf((float)cnt, 1.0f);
        unsigned ua = (unsigned)sv, ub = (unsigned)(sv >> 32);
        unsigned o0 = pack_bf2(s0 * inv + bf_lo(ua), s1 * inv + bf_hi(ua));
        unsigned o1 = pack_bf2(s2 * inv + bf_lo(ub), s3 * inv + bf_hi(ub));
        *(unsigned long long*)&Ht[row * HSTR + c * 4] =
            ((unsigned long long)o1 << 32) | o0;
    } else {
        const int g = lane >> 5;            // half 0..1
        const int c = lane & 31;            // u64 col within row
        const int row0 = wv * 4 + g;
        const int row1 = wv * 4 + 2 + g;
        const int node0 = m0 + row0, node1 = m0 + row1;
        int ns0 = 0, ne0 = 0, ns1 = 0, ne1 = 0;
        if (node0 < n) { ns0 = offsets[node0]; ne0 = offsets[node0 + 1]; }
        if (node1 < n) { ns1 = offsets[node1]; ne1 = offsets[node1 + 1]; }
        const int cnt0 = ne0 - ns0, cnt1 = ne1 - ns1;
        unsigned long long sv0 = (node0 < n) ? xt[(size_t)node0 * XSTR + c] : 0ull;
        unsigned long long sv1 = (node1 < n) ? xt[(size_t)node1 * XSTR + c] : 0ull;
        int mc0 = max(cnt0, __shfl(cnt0, lane ^ 32, 64));
        int mc1 = max(cnt1, __shfl(cnt1, lane ^ 32, 64));
        const int mcM = max(mc0, mc1);
        // prefetch first csr stripes for both nodes (issued back-to-back)
        int iiA = ns0 + (c & 15);
        if (cnt0 > 0) { if (iiA >= ne0) iiA = ne0 - 1; } else iiA = 0;
        int iiB = ns1 + (c & 15);
        if (cnt1 > 0) { if (iiB >= ne1) iiB = ne1 - 1; } else iiB = 0;
        int idx0 = (mc0 > 0) ? (int)csr_src[iiA] : 0;
        int idx1 = (mc1 > 0) ? (int)csr_src[iiB] : 0;

        float a0 = 0.f, a1 = 0.f, a2 = 0.f, a3 = 0.f;   // node0 accumulators
        float b0 = 0.f, b1 = 0.f, b2 = 0.f, b3 = 0.f;   // node1 accumulators

        for (int base = 0; base < mcM; base += 16) {
            // prefetch next csr stripes for both nodes
            int idx0N = 0, idx1N = 0;
            if (base + 16 < mc0) {
                int ii = ns0 + base + 16 + (c & 15);
                if (cnt0 > 0) { if (ii >= ne0) ii = ne0 - 1; } else ii = 0;
                idx0N = csr_src[ii];
            }
            if (base + 16 < mc1) {
                int ii = ns1 + base + 16 + (c & 15);
                if (cnt1 > 0) { if (ii >= ne1) ii = ne1 - 1; } else ii = 0;
                idx1N = csr_src[ii];
            }
            const bool do0 = base < mc0;    // wave-uniform
            const bool do1 = base < mc1;    // wave-uniform
            unsigned long long v0[16], v1[16];
            if (do0) {
#pragma unroll
                for (int q = 0; q < 16; ++q) {
                    int nb = __shfl(idx0, g * 32 + q, 64);
                    if (base + q < cnt0) v0[q] = xt[(size_t)nb * XSTR + c];
                }
            }
            if (do1) {
#pragma unroll
                for (int q = 0; q < 16; ++q) {
                    int nb = __shfl(idx1, g * 32 + q, 64);
                    if (base + q < cnt1) v1[q] = xt[(size_t)nb * XSTR + c];
                }
            }
            if (do0) {
#pragma unroll
                for (int q = 0; q < 16; ++q)
                    if (base + q < cnt0) acc4(v0[q], a0, a1, a2, a3);
            }
            if (do1) {
#pragma unroll
                for (int q = 0; q < 16; ++q)
                    if (base + q < cnt1) acc4(v1[q], b0, b1, b2, b3);
            }
            idx0 = idx0N; idx1 = idx1N;
        }
        {
            float inv = 1.0f / fmaxf((float)cnt0, 1.0f);
            unsigned ua = (unsigned)sv0, ub = (unsigned)(sv0 >> 32);
            unsigned o0 = pack_bf2(a0 * inv + bf_lo(ua), a1 * inv + bf_hi(ua));
            unsigned o1 = pack_bf2(a2 * inv + bf_lo(ub), a3 * inv + bf_hi(ub));
            *(unsigned long long*)&Ht[row0 * HSTR + c * 4] =
                ((unsigned long long)o1 << 32) | o0;
        }
        {
            float inv = 1.0f / fmaxf((float)cnt1, 1.0f);
            unsigned ua = (unsigned)sv1, ub = (unsigned)(sv1 >> 32);
            unsigned o0 = pack_bf2(b0 * inv + bf_lo(ua), b1 * inv + bf_hi(ua));
            unsigned o1 = pack_bf2(b2 * inv + bf_lo(ub), b3 * inv + bf_hi(ub));
            *(unsigned long long*)&Ht[row1 * HSTR + c * 4] =
                ((unsigned long long)o1 << 32) | o0;
        }
    }
    __syncthreads();

    // ---------- Phase B: MFMA on the 32-row tile ----------
    const int quad = lane >> 4;
    const int r16  = lane & 15;

    if (MODE == 0) {
        // 32 x F_OUT(=128): 2 row-groups x 8 col-groups = 16 tiles, 2 per wave
        const int rowg = wv & 1;
        const int cg0  = (wv >> 1) * 2;
        short8 a[KC];
#pragma unroll
        for (int c = 0; c < KC; ++c)
            a[c] = *(const short8*)&Ht[(16 * rowg + r16) * HSTR + 32 * c + quad * 8];

        floatx4 acc[2];
#pragma unroll
        for (int j = 0; j < 2; ++j)
#pragma unroll
            for (int r = 0; r < 4; ++r) acc[j][r] = 0.f;

#pragma unroll
        for (int j = 0; j < 2; ++j)
#pragma unroll
            for (int c = 0; c < KC; ++c) {
                short8 b = *(const short8*)&Wb[(size_t)(16 * (cg0 + j) + r16) * F_IN + 32 * c + quad * 8];
                acc[j] = __builtin_amdgcn_mfma_f32_16x16x32_bf16(a[c], b, acc[j], 0, 0, 0);
            }

#pragma unroll
        for (int r = 0; r < 4; ++r) {
            const int mm = m0 + 16 * rowg + quad * 4 + r;
            if (mm >= n) continue;
#pragma unroll
            for (int j = 0; j < 2; ++j) {
                const int o = 16 * (cg0 + j) + r16;
                Yb[(size_t)mm * F_OUT + o] = f2bf_rne(fmaxf(acc[j][r] + bias[o], 0.f));
            }
        }
    } else {
        // layer3: 32 x 64 = 2 x 4 tiles, 1 per wave; then heads from LDS Ytile
        const int rowg = wv & 1;
        const int cg   = wv >> 1;      // 0..3
        short8 a[KC];
#pragma unroll
        for (int c = 0; c < KC; ++c)
            a[c] = *(const short8*)&Ht[(16 * rowg + r16) * HSTR + 32 * c + quad * 8];

        floatx4 acc;
#pragma unroll
        for (int r = 0; r < 4; ++r) acc[r] = 0.f;

#pragma unroll
        for (int c = 0; c < KC; ++c) {
            short8 b = *(const short8*)&Wb[(size_t)(16 * cg + r16) * F_IN + 32 * c + quad * 8];
            acc = __builtin_amdgcn_mfma_f32_16x16x32_bf16(a[c], b, acc, 0, 0, 0);
        }

#pragma unroll
        for (int r = 0; r < 4; ++r) {
            const int lr = 16 * rowg + quad * 4 + r;
            const int mm = m0 + lr;
            const int o  = 16 * cg + r16;
            if (mm < n) {
                float v = fmaxf(acc[r] + bias[o], 0.f);
                Yf[(size_t)mm * 64 + o] = v;
                Yt[lr * 72 + o] = f2bf_rne(v);
            } else {
                Yt[lr * 72 + o] = 0;
            }
        }
        __syncthreads();

        // heads: 32 x 80 = 2 x 5 tiles = 10, waves 0..7 take t=wv, waves 0..1 also t=8+wv
        for (int t = wv; t < 10; t += 8) {
            const int rg  = t & 1;
            const int cg2 = t >> 1;    // 0..4
            short8 a2[2];
#pragma unroll
            for (int c = 0; c < 2; ++c)
                a2[c] = *(const short8*)&Yt[(16 * rg + r16) * 72 + 32 * c + quad * 8];

            floatx4 acc2;
#pragma unroll
            for (int r = 0; r < 4; ++r) acc2[r] = 0.f;

#pragma unroll
            for (int c = 0; c < 2; ++c) {
                short8 b = *(const short8*)&Whb[(size_t)(16 * cg2 + r16) * 64 + 32 * c + quad * 8];
                acc2 = __builtin_amdgcn_mfma_f32_16x16x32_bf16(a2[c], b, acc2, 0, 0, 0);
            }

#pragma unroll
            for (int r = 0; r < 4; ++r) {
                const int mm = m0 + 16 * rg + quad * 4 + r;
                if (mm >= n) continue;
                const int o = 16 * cg2 + r16;
                float v = acc2[r] + hbias[o];
                if (o < 64)      nev[(size_t)mm * 64 + o] = v;
                else if (o < 74) cls[(size_t)mm * 10 + (o - 64)] = v;
            }
        }
    }
}

// ---------------- launch ----------------

extern "C" void kernel_launch(void* const* d_in, const int* in_sizes, int n_in,
                              void* d_out, int out_size, void* d_ws, size_t ws_size,
                              hipStream_t stream) {
    const float* x  = (const float*)d_in[0];
    const int*   ei = (const int*)d_in[1];
    const float* W1 = (const float*)d_in[2];
    const float* b1 = (const float*)d_in[3];
    const float* W2 = (const float*)d_in[4];
    const float* b2 = (const float*)d_in[5];
    const float* W3 = (const float*)d_in[6];
    const float* b3 = (const float*)d_in[7];
    const float* Wp = (const float*)d_in[8];
    const float* bp = (const float*)d_in[9];
    const float* Wc = (const float*)d_in[10];
    const float* bc = (const float*)d_in[11];

    const int n = in_sizes[0] / 64;   // 50000
    const int E = in_sizes[1] / 2;    // 800000
    const int* src = ei;
    const int* dst = ei + E;

    const int items = NB * NBLK;                 // 50176
    const int nScan = (items + 255) / 256;       // 196

    // workspace layout (no memset, no global atomics)
    int* blockcnt = (int*)d_ws;                    // items
    int* base     = blockcnt + items;              // items + 1
    int* partial  = base + items + 1;              // 256
    int* offsets  = partial + 256;                 // n + 1
    unsigned int*   pairs   = (unsigned int*)(offsets + n + 1);   // E u32 (dst<<16|src)
    unsigned short* csr_src = (unsigned short*)(pairs + E);       // E u16
    uintptr_t p = (uintptr_t)(csr_src + E);
    p = (p + 255) & ~(uintptr_t)255;
    unsigned int* Hb  = (unsigned int*)p;          // n*64 (n x 128 bf16)
    unsigned int* Yb  = Hb + (size_t)n * 64;       // n*64 (n x 128 bf16)
    unsigned int* xb  = Yb + (size_t)n * 64;       // n*32 (n x 64 bf16)
    unsigned int* W1b = xb + (size_t)n * 32;       // 4096 uints
    unsigned int* W2b = W1b + 4096;                // 8192
    unsigned int* W3b = W2b + 8192;                // 4096
    unsigned int* Whb = W3b + 4096;                // 2560
    float* hbias = (float*)(Whb + 2560);           // 80

    float* out_emb = (float*)d_out;
    float* out_nev = out_emb + (size_t)n * 64;
    float* out_cls = out_nev + (size_t)n * 64;

    const int convTotal = n * 32 + 4096 + 8192 + 4096 + 2560 + 80;
    const int convBlocks = (convTotal + 255) / 256;
    prep_kernel<<<NBLK + convBlocks, 256, 0, stream>>>(
        dst, blockcnt, E,
        x, W1, W2, W3, Wp, bp, Wc, bc, xb, W1b, W2b, W3b, Whb, hbias, n * 32);

    partial_sum_kernel<<<nScan, 256, 0, stream>>>(blockcnt, partial, items);
    local_scan_kernel<<<nScan, 256, 0, stream>>>(blockcnt, partial, base, nScan, items);

    binC_kernel<<<NBLK, 256, 0, stream>>>(src, dst, base, pairs, E);
    bucketD_kernel<<<NB, 256, 0, stream>>>(pairs, base, offsets, csr_src, E, n);

    const int gF = (n + 31) / 32;    // 1563 blocks, 512 threads

    // layer 1: agg(xb, F=64) + GEMM 64->128 -> Hb (bf16)
    fused_agg_gemm_kernel<64, 128, 0><<<gF, 512, 0, stream>>>(
        (const unsigned long long*)xb, offsets, csr_src,
        (const unsigned short*)W1b, b1, (unsigned short*)Hb,
        nullptr, nullptr, nullptr, nullptr, nullptr, n);

    // layer 2: agg(Hb, F=128) + GEMM 128->128 -> Yb (bf16)
    fused_agg_gemm_kernel<128, 128, 0><<<gF, 512, 0, stream>>>(
        (const unsigned long long*)Hb, offsets, csr_src,
        (const unsigned short*)W2b, b2, (unsigned short*)Yb,
        nullptr, nullptr, nullptr, nullptr, nullptr, n);

    // layer 3: agg(Yb, F=128) + GEMM 128->64 + heads -> out_emb / nev / cls
    fused_agg_gemm_kernel<128, 64, 3><<<gF, 512, 0, stream>>>(
        (const unsigned long long*)Yb, offsets, csr_src,
        (const unsigned short*)W3b, b3, nullptr,
        out_emb, out_nev, out_cls, (const unsigned short*)Whb, hbias, n);
}

// Round 13
// 229.618 us; speedup vs baseline: 7.1228x; 1.0740x over previous
//
#include <hip/hip_runtime.h>
#include <hip/hip_bf16.h>

typedef __attribute__((ext_vector_type(8))) short short8;
typedef __attribute__((ext_vector_type(4))) float floatx4;

#define NB   196     // dst-range buckets: bkt = dst >> 8  (50000/256 -> 196)
#define NBLK 256     // edge-chunk blocks for binning

__device__ __forceinline__ float bf_lo(unsigned int u) { return __uint_as_float(u << 16); }
__device__ __forceinline__ float bf_hi(unsigned int u) { return __uint_as_float(u & 0xffff0000u); }

__device__ __forceinline__ unsigned short f2bf_rne(float f) {
    unsigned u = __float_as_uint(f);
    unsigned rb = (u >> 16) & 1u;
    u += 0x7fffu + rb;
    return (unsigned short)(u >> 16);
}
__device__ __forceinline__ unsigned int pack_bf2(float x, float y) {
    return (unsigned int)f2bf_rne(x) | ((unsigned int)f2bf_rne(y) << 16);
}

__device__ __forceinline__ void acc4(unsigned long long v, float& f0, float& f1, float& f2, float& f3) {
    unsigned ua = (unsigned)v, ub = (unsigned)(v >> 32);
    f0 += bf_lo(ua); f1 += bf_hi(ua); f2 += bf_lo(ub); f3 += bf_hi(ub);
}

// ---------------- prep: binA bucket-histogram (blocks [0,NBLK)) + convert/pack (rest) ----------------
// NO global atomics anywhere in the preamble: counting-sort with exact prefix bases.

__global__ __launch_bounds__(256) void prep_kernel(const int* __restrict__ dst,
                                                   int* __restrict__ blockcnt,   // [NB*NBLK]
                                                   int E,
                                                   const float* __restrict__ x,
                                                   const float* __restrict__ W1,
                                                   const float* __restrict__ W2,
                                                   const float* __restrict__ W3,
                                                   const float* __restrict__ Wp, const float* __restrict__ bp,
                                                   const float* __restrict__ Wc, const float* __restrict__ bc,
                                                   unsigned int* __restrict__ xb,
                                                   unsigned int* __restrict__ W1b,
                                                   unsigned int* __restrict__ W2b,
                                                   unsigned int* __restrict__ W3b,
                                                   unsigned int* __restrict__ Whb,
                                                   float* __restrict__ hbias,
                                                   int nx) {
    if ((int)blockIdx.x < NBLK) {
        __shared__ int hist[NB];
        for (int i = threadIdx.x; i < NB; i += 256) hist[i] = 0;
        __syncthreads();
        const int chunk = (E + NBLK - 1) / NBLK;
        const int lo = blockIdx.x * chunk;
        const int hi = min(lo + chunk, E);
        for (int e = lo + threadIdx.x; e < hi; e += 256)
            atomicAdd(&hist[dst[e] >> 8], 1);          // LDS atomic, block-local
        __syncthreads();
        for (int i = threadIdx.x; i < NB; i += 256)
            blockcnt[i * NBLK + blockIdx.x] = hist[i]; // bucket-major layout for scan
        return;
    }
    int i = (blockIdx.x - NBLK) * 256 + threadIdx.x;
    const int T0 = nx;            // x pairs
    const int T1 = T0 + 4096;     // W1 128x64
    const int T2 = T1 + 8192;     // W2 128x128
    const int T3 = T2 + 4096;     // W3 64x128
    const int T4 = T3 + 2560;     // Whb 80x64
    const int T5 = T4 + 80;       // hbias
    if (i < T0) {
        float2 f = ((const float2*)x)[i];
        xb[i] = pack_bf2(f.x, f.y);
    } else if (i < T1) {
        float2 f = ((const float2*)W1)[i - T0];
        W1b[i - T0] = pack_bf2(f.x, f.y);
    } else if (i < T2) {
        float2 f = ((const float2*)W2)[i - T1];
        W2b[i - T1] = pack_bf2(f.x, f.y);
    } else if (i < T3) {
        float2 f = ((const float2*)W3)[i - T2];
        W3b[i - T2] = pack_bf2(f.x, f.y);
    } else if (i < T4) {
        int j = i - T3;
        int r = j >> 5, c = (j & 31) * 2;
        float v0 = 0.f, v1 = 0.f;
        if (r < 64)      { v0 = Wp[r * 64 + c]; v1 = Wp[r * 64 + c + 1]; }
        else if (r < 74) { v0 = Wc[(r - 64) * 64 + c]; v1 = Wc[(r - 64) * 64 + c + 1]; }
        Whb[j] = pack_bf2(v0, v1);
    } else if (i < T5) {
        int j = i - T4;
        float v = 0.f;
        if (j < 64)      v = bp[j];
        else if (j < 74) v = bc[j - 64];
        hbias[j] = v;
    }
}

// ---------------- scan over blockcnt (items = NB*NBLK) -> exact exclusive base ----------------

__global__ __launch_bounds__(256) void partial_sum_kernel(const int* __restrict__ v,
                                                          int* __restrict__ partial, int n) {
    __shared__ int s[256];
    int t = threadIdx.x;
    int i = blockIdx.x * 256 + t;
    s[t] = (i < n) ? v[i] : 0;
    __syncthreads();
    for (int off = 128; off > 0; off >>= 1) {
        if (t < off) s[t] += s[t + off];
        __syncthreads();
    }
    if (t == 0) partial[blockIdx.x] = s[0];
}

__global__ __launch_bounds__(256) void local_scan_kernel(const int* __restrict__ v,
                                                         const int* __restrict__ partial,
                                                         int* __restrict__ base,
                                                         int nblocks, int n) {
    __shared__ int sp[256];
    __shared__ int s[256];
    int t = threadIdx.x;
    sp[t] = (t < nblocks) ? partial[t] : 0;
    __syncthreads();
    for (int off = 1; off < 256; off <<= 1) {
        int u = (t >= off) ? sp[t - off] : 0;
        __syncthreads();
        sp[t] += u;
        __syncthreads();
    }
    const int blockbase = (blockIdx.x == 0) ? 0 : sp[blockIdx.x - 1];
    if (blockIdx.x == 0 && t == 0) base[n] = sp[nblocks - 1];   // total = E

    int i = blockIdx.x * 256 + t;
    int w = (i < n) ? v[i] : 0;
    s[t] = w;
    __syncthreads();
    for (int off = 1; off < 256; off <<= 1) {
        int u = (t >= off) ? s[t - off] : 0;
        __syncthreads();
        s[t] += u;
        __syncthreads();
    }
    if (i < n) base[i] = blockbase + s[t] - w;   // exclusive prefix
}

// ---------------- binC: rank within (block,bucket) in LDS, write packed pairs ----------------

__global__ __launch_bounds__(256) void binC_kernel(const int* __restrict__ src,
                                                   const int* __restrict__ dst,
                                                   const int* __restrict__ base,
                                                   unsigned int* __restrict__ pairs, int E) {
    __shared__ int bbase[NB];
    __shared__ int cur[NB];
    for (int i = threadIdx.x; i < NB; i += 256) {
        bbase[i] = base[i * NBLK + blockIdx.x];
        cur[i] = 0;
    }
    __syncthreads();
    const int chunk = (E + NBLK - 1) / NBLK;
    const int lo = blockIdx.x * chunk;
    const int hi = min(lo + chunk, E);
    for (int e = lo + threadIdx.x; e < hi; e += 256) {
        int d = dst[e];
        int b = d >> 8;
        int r = atomicAdd(&cur[b], 1);                 // LDS atomic, block-local
        pairs[bbase[b] + r] = ((unsigned)d << 16) | (unsigned)src[e];
    }
}

// ---------------- bucketD: per-node count+scan in LDS -> offsets + csr scatter ----------------
// One block per bucket; bucket b owns nodes [b<<8, (b+1)<<8). Region is contiguous.

__global__ __launch_bounds__(256) void bucketD_kernel(const unsigned int* __restrict__ pairs,
                                                      const int* __restrict__ base,
                                                      int* __restrict__ offsets,
                                                      unsigned short* __restrict__ csr_src,
                                                      int E, int n) {
    __shared__ int cnt[256];
    __shared__ int loc[256];
    const int b = blockIdx.x;
    const int start = base[b * NBLK];
    const int end   = base[(b + 1) * NBLK];   // b=NB-1 reads base[NB*NBLK] = E (written by scan)
    const int t = threadIdx.x;

    cnt[t] = 0;
    __syncthreads();
    for (int i = start + t; i < end; i += 256)
        atomicAdd(&cnt[(pairs[i] >> 16) & 255], 1);    // local node index = dst & 255
    __syncthreads();

    // inclusive scan of cnt -> loc
    loc[t] = cnt[t];
    __syncthreads();
    for (int off = 1; off < 256; off <<= 1) {
        int u = (t >= off) ? loc[t - off] : 0;
        __syncthreads();
        loc[t] += u;
        __syncthreads();
    }
    const int excl = (t == 0) ? 0 : loc[t - 1];

    const int d = (b << 8) + t;
    if (d < n) offsets[d] = start + excl;
    if (b == 0 && t == 0) offsets[n] = E;

    __syncthreads();
    cnt[t] = excl;            // cursor = local exclusive prefix
    __syncthreads();
    for (int i = start + t; i < end; i += 256) {
        unsigned pr = pairs[i];
        int j = (pr >> 16) & 255;
        int p = atomicAdd(&cnt[j], 1);                 // LDS atomic, block-local
        csr_src[start + p] = (unsigned short)(pr & 0xffffu);
    }
}

// ---------------- Fused agg + MFMA GEMM per layer ----------------
// Block = 512 threads (8 waves), 32 nodes. Phase A: one node per LANE GROUP —
// F=64: 4 nodes/wave (16-lane groups), F=128: 2 nodes/pass (32-lane halves, 2
// passes). Uniform stripe loop (16 edges/stripe) with v[16] batches. Per-node edge
// accumulation strictly sequential; stripe loop bound mc is wave-uniform (shfl-max),
// so all __shfl sources are active. NOTE: measured ~47us across SIX structural
// variants at ~1.7-2.3TB/s TCC-fetch -> the random-line L2-fill floor for this
// access pattern (79MB fetched/layer from a 12.8MB table over 8 non-coherent L2s).
// Phase B: 8 waves MFMA the 32xF_OUT tile from LDS.
// MODE 0: bf16 out + relu.  MODE 3: relu, fp32 emb out, heads MFMA via LDS Ytile.

template <int F_IN, int F_OUT, int MODE>
__global__ __launch_bounds__(512) void fused_agg_gemm_kernel(
        const unsigned long long* __restrict__ xt,      // gather table, F_IN/4 u64 per row
        const int* __restrict__ offsets,
        const unsigned short* __restrict__ csr_src,
        const unsigned short* __restrict__ Wb,          // F_OUT x F_IN bf16
        const float* __restrict__ bias,
        unsigned short* __restrict__ Yb,                // MODE 0 out
        float* __restrict__ Yf,                         // MODE 3: emb out (fp32)
        float* __restrict__ nev, float* __restrict__ cls,
        const unsigned short* __restrict__ Whb, const float* __restrict__ hbias,
        int n) {
    constexpr int KC   = F_IN / 32;     // short8 chunks per row
    constexpr int XSTR = F_IN / 4;      // u64 per gather-table row
    constexpr int HSTR = F_IN + 8;      // LDS row stride (shorts), breaks pow2 banks
    __shared__ __align__(16) unsigned short Ht[32 * HSTR];
    __shared__ __align__(16) unsigned short Yt[(MODE == 3) ? 32 * 72 : 16];

    const int lane = threadIdx.x & 63;
    const int wv   = threadIdx.x >> 6;      // 0..7
    const int m0   = blockIdx.x * 32;

    // ---------- Phase A ----------
    if (F_IN == 64) {
        const int g   = lane >> 4;          // node group 0..3
        const int c   = lane & 15;          // u64 col within row
        const int row = wv * 4 + g;
        const int node = m0 + row;
        int ns = 0, ne = 0;
        if (node < n) { ns = offsets[node]; ne = offsets[node + 1]; }
        const int cnt = ne - ns;
        unsigned long long sv = (node < n) ? xt[(size_t)node * XSTR + c] : 0ull;

        int mc = cnt;
        mc = max(mc, __shfl(mc, lane ^ 16, 64));
        mc = max(mc, __shfl(mc, lane ^ 32, 64));    // wave-max edge count

        float s0 = 0.f, s1 = 0.f, s2 = 0.f, s3 = 0.f;
        int ii0 = ns + c;
        if (cnt > 0) { if (ii0 >= ne) ii0 = ne - 1; } else ii0 = 0;
        int idx = (mc > 0) ? (int)csr_src[ii0] : 0;

        for (int base = 0; base < mc; base += 16) {
            int idxN = 0;                            // prefetch next stripe's csr
            if (base + 16 < mc) {
                int ii = ns + base + 16 + c;
                if (cnt > 0) { if (ii >= ne) ii = ne - 1; } else ii = 0;
                idxN = csr_src[ii];
            }
            unsigned long long v[16];
#pragma unroll
            for (int q = 0; q < 16; ++q) {
                int nb = __shfl(idx, g * 16 + q, 64);   // all lanes execute
                if (base + q < cnt) v[q] = xt[(size_t)nb * XSTR + c];
            }
#pragma unroll
            for (int q = 0; q < 16; ++q)
                if (base + q < cnt) acc4(v[q], s0, s1, s2, s3);
            idx = idxN;
        }
        float inv = 1.0f / fmaxf((float)cnt, 1.0f);
        unsigned ua = (unsigned)sv, ub = (unsigned)(sv >> 32);
        unsigned o0 = pack_bf2(s0 * inv + bf_lo(ua), s1 * inv + bf_hi(ua));
        unsigned o1 = pack_bf2(s2 * inv + bf_lo(ub), s3 * inv + bf_hi(ub));
        *(unsigned long long*)&Ht[row * HSTR + c * 4] =
            ((unsigned long long)o1 << 32) | o0;
    } else {
        const int g = lane >> 5;            // half 0..1
        const int c = lane & 31;            // u64 col within row
        const int row0 = wv * 4 + g;
        const int row1 = wv * 4 + 2 + g;
        const int node0 = m0 + row0, node1 = m0 + row1;
        int ns0 = 0, ne0 = 0, ns1 = 0, ne1 = 0;
        if (node0 < n) { ns0 = offsets[node0]; ne0 = offsets[node0 + 1]; }
        if (node1 < n) { ns1 = offsets[node1]; ne1 = offsets[node1 + 1]; }
        const int cnt0 = ne0 - ns0, cnt1 = ne1 - ns1;
        unsigned long long sv0 = (node0 < n) ? xt[(size_t)node0 * XSTR + c] : 0ull;
        unsigned long long sv1 = (node1 < n) ? xt[(size_t)node1 * XSTR + c] : 0ull;
        int mc0 = max(cnt0, __shfl(cnt0, lane ^ 32, 64));
        int mc1 = max(cnt1, __shfl(cnt1, lane ^ 32, 64));
        // prefetch first csr stripes for both passes (issued back-to-back)
        int iiA = ns0 + (c & 15);
        if (cnt0 > 0) { if (iiA >= ne0) iiA = ne0 - 1; } else iiA = 0;
        int iiB = ns1 + (c & 15);
        if (cnt1 > 0) { if (iiB >= ne1) iiB = ne1 - 1; } else iiB = 0;
        int idx0 = (mc0 > 0) ? (int)csr_src[iiA] : 0;
        int idx1 = (mc1 > 0) ? (int)csr_src[iiB] : 0;

        // pass 0: nodes row0 (both halves)
        {
            float s0 = 0.f, s1 = 0.f, s2 = 0.f, s3 = 0.f;
            int idx = idx0;
            for (int base = 0; base < mc0; base += 16) {
                int idxN = 0;
                if (base + 16 < mc0) {
                    int ii = ns0 + base + 16 + (c & 15);
                    if (cnt0 > 0) { if (ii >= ne0) ii = ne0 - 1; } else ii = 0;
                    idxN = csr_src[ii];
                }
                unsigned long long v[16];
#pragma unroll
                for (int q = 0; q < 16; ++q) {
                    int nb = __shfl(idx, g * 32 + q, 64);
                    if (base + q < cnt0) v[q] = xt[(size_t)nb * XSTR + c];
                }
#pragma unroll
                for (int q = 0; q < 16; ++q)
                    if (base + q < cnt0) acc4(v[q], s0, s1, s2, s3);
                idx = idxN;
            }
            float inv = 1.0f / fmaxf((float)cnt0, 1.0f);
            unsigned ua = (unsigned)sv0, ub = (unsigned)(sv0 >> 32);
            unsigned o0 = pack_bf2(s0 * inv + bf_lo(ua), s1 * inv + bf_hi(ua));
            unsigned o1 = pack_bf2(s2 * inv + bf_lo(ub), s3 * inv + bf_hi(ub));
            *(unsigned long long*)&Ht[row0 * HSTR + c * 4] =
                ((unsigned long long)o1 << 32) | o0;
        }
        // pass 1: nodes row1 (both halves)
        {
            float s0 = 0.f, s1 = 0.f, s2 = 0.f, s3 = 0.f;
            int idx = idx1;
            for (int base = 0; base < mc1; base += 16) {
                int idxN = 0;
                if (base + 16 < mc1) {
                    int ii = ns1 + base + 16 + (c & 15);
                    if (cnt1 > 0) { if (ii >= ne1) ii = ne1 - 1; } else ii = 0;
                    idxN = csr_src[ii];
                }
                unsigned long long v[16];
#pragma unroll
                for (int q = 0; q < 16; ++q) {
                    int nb = __shfl(idx, g * 32 + q, 64);
                    if (base + q < cnt1) v[q] = xt[(size_t)nb * XSTR + c];
                }
#pragma unroll
                for (int q = 0; q < 16; ++q)
                    if (base + q < cnt1) acc4(v[q], s0, s1, s2, s3);
                idx = idxN;
            }
            float inv = 1.0f / fmaxf((float)cnt1, 1.0f);
            unsigned ua = (unsigned)sv1, ub = (unsigned)(sv1 >> 32);
            unsigned o0 = pack_bf2(s0 * inv + bf_lo(ua), s1 * inv + bf_hi(ua));
            unsigned o1 = pack_bf2(s2 * inv + bf_lo(ub), s3 * inv + bf_hi(ub));
            *(unsigned long long*)&Ht[row1 * HSTR + c * 4] =
                ((unsigned long long)o1 << 32) | o0;
        }
    }
    __syncthreads();

    // ---------- Phase B: MFMA on the 32-row tile ----------
    const int quad = lane >> 4;
    const int r16  = lane & 15;

    if (MODE == 0) {
        // 32 x F_OUT(=128): 2 row-groups x 8 col-groups = 16 tiles, 2 per wave
        const int rowg = wv & 1;
        const int cg0  = (wv >> 1) * 2;
        short8 a[KC];
#pragma unroll
        for (int c = 0; c < KC; ++c)
            a[c] = *(const short8*)&Ht[(16 * rowg + r16) * HSTR + 32 * c + quad * 8];

        floatx4 acc[2];
#pragma unroll
        for (int j = 0; j < 2; ++j)
#pragma unroll
            for (int r = 0; r < 4; ++r) acc[j][r] = 0.f;

#pragma unroll
        for (int j = 0; j < 2; ++j)
#pragma unroll
            for (int c = 0; c < KC; ++c) {
                short8 b = *(const short8*)&Wb[(size_t)(16 * (cg0 + j) + r16) * F_IN + 32 * c + quad * 8];
                acc[j] = __builtin_amdgcn_mfma_f32_16x16x32_bf16(a[c], b, acc[j], 0, 0, 0);
            }

#pragma unroll
        for (int r = 0; r < 4; ++r) {
            const int mm = m0 + 16 * rowg + quad * 4 + r;
            if (mm >= n) continue;
#pragma unroll
            for (int j = 0; j < 2; ++j) {
                const int o = 16 * (cg0 + j) + r16;
                Yb[(size_t)mm * F_OUT + o] = f2bf_rne(fmaxf(acc[j][r] + bias[o], 0.f));
            }
        }
    } else {
        // layer3: 32 x 64 = 2 x 4 tiles, 1 per wave; then heads from LDS Ytile
        const int rowg = wv & 1;
        const int cg   = wv >> 1;      // 0..3
        short8 a[KC];
#pragma unroll
        for (int c = 0; c < KC; ++c)
            a[c] = *(const short8*)&Ht[(16 * rowg + r16) * HSTR + 32 * c + quad * 8];

        floatx4 acc;
#pragma unroll
        for (int r = 0; r < 4; ++r) acc[r] = 0.f;

#pragma unroll
        for (int c = 0; c < KC; ++c) {
            short8 b = *(const short8*)&Wb[(size_t)(16 * cg + r16) * F_IN + 32 * c + quad * 8];
            acc = __builtin_amdgcn_mfma_f32_16x16x32_bf16(a[c], b, acc, 0, 0, 0);
        }

#pragma unroll
        for (int r = 0; r < 4; ++r) {
            const int lr = 16 * rowg + quad * 4 + r;
            const int mm = m0 + lr;
            const int o  = 16 * cg + r16;
            if (mm < n) {
                float v = fmaxf(acc[r] + bias[o], 0.f);
                Yf[(size_t)mm * 64 + o] = v;
                Yt[lr * 72 + o] = f2bf_rne(v);
            } else {
                Yt[lr * 72 + o] = 0;
            }
        }
        __syncthreads();

        // heads: 32 x 80 = 2 x 5 tiles = 10, waves 0..7 take t=wv, waves 0..1 also t=8+wv
        for (int t = wv; t < 10; t += 8) {
            const int rg  = t & 1;
            const int cg2 = t >> 1;    // 0..4
            short8 a2[2];
#pragma unroll
            for (int c = 0; c < 2; ++c)
                a2[c] = *(const short8*)&Yt[(16 * rg + r16) * 72 + 32 * c + quad * 8];

            floatx4 acc2;
#pragma unroll
            for (int r = 0; r < 4; ++r) acc2[r] = 0.f;

#pragma unroll
            for (int c = 0; c < 2; ++c) {
                short8 b = *(const short8*)&Whb[(size_t)(16 * cg2 + r16) * 64 + 32 * c + quad * 8];
                acc2 = __builtin_amdgcn_mfma_f32_16x16x32_bf16(a2[c], b, acc2, 0, 0, 0);
            }

#pragma unroll
            for (int r = 0; r < 4; ++r) {
                const int mm = m0 + 16 * rg + quad * 4 + r;
                if (mm >= n) continue;
                const int o = 16 * cg2 + r16;
                float v = acc2[r] + hbias[o];
                if (o < 64)      nev[(size_t)mm * 64 + o] = v;
                else if (o < 74) cls[(size_t)mm * 10 + (o - 64)] = v;
            }
        }
    }
}

// ---------------- launch ----------------

extern "C" void kernel_launch(void* const* d_in, const int* in_sizes, int n_in,
                              void* d_out, int out_size, void* d_ws, size_t ws_size,
                              hipStream_t stream) {
    const float* x  = (const float*)d_in[0];
    const int*   ei = (const int*)d_in[1];
    const float* W1 = (const float*)d_in[2];
    const float* b1 = (const float*)d_in[3];
    const float* W2 = (const float*)d_in[4];
    const float* b2 = (const float*)d_in[5];
    const float* W3 = (const float*)d_in[6];
    const float* b3 = (const float*)d_in[7];
    const float* Wp = (const float*)d_in[8];
    const float* bp = (const float*)d_in[9];
    const float* Wc = (const float*)d_in[10];
    const float* bc = (const float*)d_in[11];

    const int n = in_sizes[0] / 64;   // 50000
    const int E = in_sizes[1] / 2;    // 800000
    const int* src = ei;
    const int* dst = ei + E;

    const int items = NB * NBLK;                 // 50176
    const int nScan = (items + 255) / 256;       // 196

    // workspace layout (no memset, no global atomics)
    int* blockcnt = (int*)d_ws;                    // items
    int* base     = blockcnt + items;              // items + 1
    int* partial  = base + items + 1;              // 256
    int* offsets  = partial + 256;                 // n + 1
    unsigned int*   pairs   = (unsigned int*)(offsets + n + 1);   // E u32 (dst<<16|src)
    unsigned short* csr_src = (unsigned short*)(pairs + E);       // E u16
    uintptr_t p = (uintptr_t)(csr_src + E);
    p = (p + 255) & ~(uintptr_t)255;
    unsigned int* Hb  = (unsigned int*)p;          // n*64 (n x 128 bf16)
    unsigned int* Yb  = Hb + (size_t)n * 64;       // n*64 (n x 128 bf16)
    unsigned int* xb  = Yb + (size_t)n * 64;       // n*32 (n x 64 bf16)
    unsigned int* W1b = xb + (size_t)n * 32;       // 4096 uints
    unsigned int* W2b = W1b + 4096;                // 8192
    unsigned int* W3b = W2b + 8192;                // 4096
    unsigned int* Whb = W3b + 4096;                // 2560
    float* hbias = (float*)(Whb + 2560);           // 80

    float* out_emb = (float*)d_out;
    float* out_nev = out_emb + (size_t)n * 64;
    float* out_cls = out_nev + (size_t)n * 64;

    const int convTotal = n * 32 + 4096 + 8192 + 4096 + 2560 + 80;
    const int convBlocks = (convTotal + 255) / 256;
    prep_kernel<<<NBLK + convBlocks, 256, 0, stream>>>(
        dst, blockcnt, E,
        x, W1, W2, W3, Wp, bp, Wc, bc, xb, W1b, W2b, W3b, Whb, hbias, n * 32);

    partial_sum_kernel<<<nScan, 256, 0, stream>>>(blockcnt, partial, items);
    local_scan_kernel<<<nScan, 256, 0, stream>>>(blockcnt, partial, base, nScan, items);

    binC_kernel<<<NBLK, 256, 0, stream>>>(src, dst, base, pairs, E);
    bucketD_kernel<<<NB, 256, 0, stream>>>(pairs, base, offsets, csr_src, E, n);

    const int gF = (n + 31) / 32;    // 1563 blocks, 512 threads

    // layer 1: agg(xb, F=64) + GEMM 64->128 -> Hb (bf16)
    fused_agg_gemm_kernel<64, 128, 0><<<gF, 512, 0, stream>>>(
        (const unsigned long long*)xb, offsets, csr_src,
        (const unsigned short*)W1b, b1, (unsigned short*)Hb,
        nullptr, nullptr, nullptr, nullptr, nullptr, n);

    // layer 2: agg(Hb, F=128) + GEMM 128->128 -> Yb (bf16)
    fused_agg_gemm_kernel<128, 128, 0><<<gF, 512, 0, stream>>>(
        (const unsigned long long*)Hb, offsets, csr_src,
        (const unsigned short*)W2b, b2, (unsigned short*)Yb,
        nullptr, nullptr, nullptr, nullptr, nullptr, n);

    // layer 3: agg(Yb, F=128) + GEMM 128->64 + heads -> out_emb / nev / cls
    fused_agg_gemm_kernel<128, 64, 3><<<gF, 512, 0, stream>>>(
        (const unsigned long long*)Yb, offsets, csr_src,
        (const unsigned short*)W3b, b3, nullptr,
        out_emb, out_nev, out_cls, (const unsigned short*)Whb, hbias, n);
}